// Round 4
// baseline (219.592 us; speedup 1.0000x reference)
//
#include <hip/hip_runtime.h>
#include <stdint.h>

// LocalCorrelation on MI355X (gfx950).  R10 = R9 with the nt2_kernel blockIdx
// bitfield decode FIXED.  R9 crashed: bb=(bid>>8)&3 overlapped kg's bit 8 and
// tens=bid>>10 reached 3 with grid 4096 -> P read up to (tens*4+bb)=15 planes
// = ~7.9 MB into the 4 MB partials buffer at the END of d_out -> OOB read ->
// GPU fault.  Correct decode: rg(bits 0-5), kg(6-8), bb(9-10), tens(11).
// Theory unchanged from R9: nt was DRAM-scatter-bound (R8 proved not latency-
// starved); split into two pure-streaming passes.  Pass A: 4KB-contiguous
// plane slices, per-px sumsq in regs, partials in d_out tail (dead space,
// corr overwrites afterwards).  Pass B: (pxg,ccg) lane mapping forms 8-c fp16
// chunks in registers; each 4-lane group stores one FULL 64B line.
// corr kernel unchanged from R5 (passed, conflict-free).

typedef _Float16 half8 __attribute__((ext_vector_type(8)));
typedef float floatx4 __attribute__((ext_vector_type(4)));

#define B_ 4
#define C_ 256
#define H_ 128
#define W_ 128
#define K2_ 169
#define INV_T 14.285714285714286f
#define KGS (H_ * W_ * 32)   // element stride between kg planes (per b)
#define HW_ (H_ * W_)        // 16384
#define P_OFF 40108032       // byte offset of partials in d_out (44302336 - 4MB)

static __device__ __forceinline__ void gload16(const void* g, void* l) {
  __builtin_amdgcn_global_load_lds((const __attribute__((address_space(1))) void*)g,
                                   (__attribute__((address_space(3))) void*)l, 16, 0, 0);
}

// ---------------- Pass A: per-pixel sumsq partials (streaming) ----------------
// Block = (tens, b, c-slice of 32, 8 rows).  1024 blocks x 256 thr.
// Thread owns 4 px (float4); loops 32 planes reading 4KB-contiguous slices.
// P[tens][b][cs][16384 px] f32 = 4 MB, placed in d_out tail (dead until corr).
__global__ __launch_bounds__(256, 8) void norm_kernel(const float* __restrict__ fa,
                                                      const float* __restrict__ fb,
                                                      float* __restrict__ P) {
  const int bid = blockIdx.x;
  const int rg = bid & 15, cs = (bid >> 4) & 7, bb = (bid >> 7) & 3, tens = bid >> 9;
  const float* __restrict__ src = tens ? fb : fa;
  const int t = threadIdx.x;
  const float* gs = src + ((size_t)bb * C_ + cs * 32) * HW_ + rg * 1024 + t * 4;
  floatx4 acc = {0.f, 0.f, 0.f, 0.f};
  #pragma unroll
  for (int cc = 0; cc < 32; ++cc) {
    const floatx4 v = *(const floatx4*)(gs + (size_t)cc * HW_);
    acc += v * v;
  }
  *(floatx4*)(P + ((((size_t)tens * 4 + bb) * 8 + cs) * HW_) + rg * 1024 + t * 4) = acc;
}

// ---------------- Pass B: normalize + transpose (streaming) ----------------
// Block = (tens, b, kg of 32 c, 2 rows = 256 px).  4096 blocks x 256 thr.
// Decode: rg bits 0-5, kg bits 6-8, bb bits 9-10, tens bit 11.
// Lane l: pxg = l>>2 (4 px), ccg = l&3 (8-c group).  Per plane instr: 16 pxg
// x 16B = 256B contiguous per each of 4 ccg planes.  Store: 4-lane group
// (fixed pxg, ccg 0..3) writes bytes {0,16,32,48} of one px row = full 64B
// line per instruction.  No LDS.
__global__ __launch_bounds__(256, 6) void nt2_kernel(const float* __restrict__ fa,
                                                     const float* __restrict__ fb,
                                                     const float* __restrict__ P,
                                                     _Float16* __restrict__ an,
                                                     _Float16* __restrict__ bn) {
  const int bid = blockIdx.x;
  const int rg = bid & 63, kg = (bid >> 6) & 7, bb = (bid >> 9) & 3, tens = bid >> 11;
  const float* __restrict__ src = tens ? fb : fa;
  _Float16* __restrict__ dst = tens ? bn : an;
  const int t = threadIdx.x;
  const int w = t >> 6, l = t & 63, pxg = l >> 2, ccg = l & 3;
  const int pxq = rg * 256 + w * 64 + pxg * 4;  // base of this lane's 4 px

  // inv-norm for the 4 px (sum 8 partial slices; 4-lane groups broadcast-read)
  const float* Pb = P + (((size_t)tens * 4 + bb) * 8) * HW_ + pxq;
  floatx4 s = {0.f, 0.f, 0.f, 0.f};
  #pragma unroll
  for (int cs = 0; cs < 8; ++cs) s += *(const floatx4*)(Pb + (size_t)cs * HW_);
  const float sc = tens ? 1.0f : INV_T;  // fold 1/T into a
  float inv[4];
  #pragma unroll
  for (int j = 0; j < 4; ++j) inv[j] = sc / fmaxf(sqrtf(s[j]), 1e-12f);

  // read this lane's 8 planes (c = kg*32 + ccg*8 + cc) for its 4 px
  const float* gs = src + ((size_t)bb * C_ + kg * 32 + ccg * 8) * HW_ + pxq;
  floatx4 v[8];
  #pragma unroll
  for (int cc = 0; cc < 8; ++cc) v[cc] = *(const floatx4*)(gs + (size_t)cc * HW_);

  // pack per-px 8-c fp16 chunks in registers and store full 64B lines
  _Float16* db = dst + ((size_t)bb * 8 + kg) * (size_t)HW_ * 32;
  #pragma unroll
  for (int j = 0; j < 4; ++j) {
    half8 h;
    #pragma unroll
    for (int cc = 0; cc < 8; ++cc) h[cc] = (_Float16)(v[cc][j] * inv[j]);
    *(half8*)(db + (size_t)(pxq + j) * 32 + ccg * 8) = h;
  }
}

// ---------------- Pass 2: band-GEMM correlation (unchanged from R5) ----------------
// Per 32 KB buffer, LDS byte offset of job = job*16:
//   b-halo jobs [0, 28672): job = (row*28+col)*4+qt ; a jobs [28672, 32768).
// Frag reads (hw): A[r] at 14336 + (r*16+ml)*32 + q*8 ; B at jj*896 + col*32 + q*8.
union SmemU { _Float16 stage[2][16384]; float ostage[K2_ * 2 * 17]; };  // 64 KB

__global__ __launch_bounds__(512, 4) void corr_kernel(const _Float16* __restrict__ an,
                                                      const _Float16* __restrict__ bn,
                                                      float* __restrict__ out) {
  __shared__ SmemU u;
  const int bid = blockIdx.x;
  const int xcd = bid & 7, l = bid >> 3;  // XCD-contiguous h-bands
  const int bb = l >> 5, hseg = (l >> 3) & 3, wt = l & 7;
  const int hg = xcd * 4 + hseg;
  const int h0 = hg * 4, w0 = wt * 16;
  const int t = threadIdx.x;
  const int lane = t & 63, wv = t >> 6;  // 8 waves
  const int ml = lane & 15, q = lane >> 4;
  const int ntile = wv & 1, jjg = wv >> 1;

  const _Float16* ptr[4];
  unsigned flags = 0u;
  #pragma unroll
  for (int j = 0; j < 4; ++j) {
    const int job = j * 512 + t;
    if (job < 1792) {  // b-halo: 16 rows x 28 cols x 4 quarters
      const int row = job / 112, rem = job - row * 112;
      const int col = rem >> 2, qt = rem & 3;
      const int rim = h0 - 6 + row, cim = w0 - 6 + col;
      const bool ok = ((unsigned)rim < (unsigned)H_) && ((unsigned)cim < (unsigned)W_);
      ptr[j] = bn + (((size_t)bb * 8 * H_ + (ok ? rim : 0)) * W_ + (ok ? cim : 0)) * 32 + qt * 8;
      if (ok) flags |= 1u << j;
    } else {           // a-tile: 64 px (r*16+m) x 4 quarters
      const int aj = job - 1792;
      const int px = aj >> 2, qt = aj & 3;
      const int r = px >> 4, m = px & 15;
      ptr[j] = an + (((size_t)bb * 8 * H_ + h0 + r) * W_ + w0 + m) * 32 + qt * 8;
      flags |= 1u << j;
    }
  }

  const uint4 z4 = make_uint4(0u, 0u, 0u, 0u);
  #pragma unroll
  for (int j = 0; j < 4; ++j) {
    *(uint4*)((char*)u.stage[0] + (j * 512 + t) * 16) = z4;
    *(uint4*)((char*)u.stage[1] + (j * 512 + t) * 16) = z4;
  }
  __syncthreads();

  #pragma unroll
  for (int j = 0; j < 4; ++j) {
    if (flags & (1u << j))
      gload16(ptr[j], (char*)u.stage[0] + (j * 512 + wv * 64) * 16);
    ptr[j] += KGS;
  }

  floatx4 acc[4][4] = {};  // [uu: jj=jjg+4uu][r]; 13 of 16 valid per wave

  for (int kg = 0; kg < 8; ++kg) {
    __syncthreads();  // drains kg's DMA; all kg-1 frag reads already complete
    if (kg < 7) {
      char* nb = (char*)u.stage[(kg + 1) & 1];
      #pragma unroll
      for (int j = 0; j < 4; ++j) {
        if (flags & (1u << j))
          gload16(ptr[j], nb + (j * 512 + wv * 64) * 16);
        ptr[j] += KGS;
      }
    }
    const _Float16* sb = u.stage[kg & 1];

    half8 A[4];
    #pragma unroll
    for (int r = 0; r < 4; ++r)
      A[r] = *(const half8*)(sb + 14336 + (r * 16 + ml) * 32 + q * 8);

    #pragma unroll
    for (int uu = 0; uu < 4; ++uu) {
      const int jj = jjg + 4 * uu;
      const half8 Bf = *(const half8*)(sb + jj * 896 + (ntile * 16 + ml) * 32 + q * 8);
      #pragma unroll
      for (int r = 0; r < 4; ++r) {
        if ((uu == 0 && r > jjg) || (uu == 3 && r < jjg)) continue;  // dy out of band
        acc[uu][r] = __builtin_amdgcn_mfma_f32_16x16x32_f16(A[r], Bf, acc[uu][r], 0, 0, 0);
      }
    }
  }

  // ---- epilogue: 2 rounds of 2 rows; ostage (22984 B) overlays buf0 only ----
  #pragma unroll
  for (int r2 = 0; r2 < 2; ++r2) {
    if (r2) __syncthreads();
    #pragma unroll
    for (int uu = 0; uu < 4; ++uu) {
      const int jj = jjg + 4 * uu;
      const int col = ntile * 16 + ml;
      #pragma unroll
      for (int rr = 2 * r2; rr < 2 * r2 + 2; ++rr) {
        if ((uu == 0 && rr > jjg) || (uu == 3 && rr < jjg)) continue;
        const int dy6 = jj - rr;  // in [0,12]
        #pragma unroll
        for (int p = 0; p < 4; ++p) {
          const int ip = q * 4 + p;
          const int dx6 = col - ip;
          if (dx6 >= 0 && dx6 <= 12)
            u.ostage[((dy6 * 13 + dx6) * 2 + (rr & 1)) * 17 + ip] = acc[uu][rr][p];
        }
      }
    }
    __syncthreads();
    for (int s = t; s < K2_ * 32; s += 512) {
      const int k = s >> 5, r1 = (s >> 4) & 1, ip = s & 15;
      out[(((size_t)bb * K2_ + k) * H_ + h0 + 2 * r2 + r1) * W_ + w0 + ip] =
          u.ostage[(k * 2 + r1) * 17 + ip];
    }
  }
}

extern "C" void kernel_launch(void* const* d_in, const int* in_sizes, int n_in,
                              void* d_out, int out_size, void* d_ws, size_t ws_size,
                              hipStream_t stream) {
  const float* fa = (const float*)d_in[0];
  const float* fb = (const float*)d_in[1];
  float* out = (float*)d_out;
  float* P = (float*)((char*)d_out + P_OFF);      // 4 MB partials, dead after nt2
  _Float16* an = (_Float16*)d_ws;                 // 33.55 MB, [b][kg][h][w][32]
  _Float16* bn = an + (size_t)B_ * H_ * W_ * C_;  // 33.55 MB
  norm_kernel<<<1024, 256, 0, stream>>>(fa, fb, P);
  nt2_kernel<<<4096, 256, 0, stream>>>(fa, fb, P, an, bn);
  corr_kernel<<<1024, 512, 0, stream>>>(an, bn, out);
}

// Round 6
// 210.886 us; speedup vs baseline: 1.0413x; 1.0413x over previous
//
#include <hip/hip_runtime.h>
#include <stdint.h>

// LocalCorrelation on MI355X (gfx950).  R12 = R11 resubmitted verbatim after
// a full correctness audit (container failed twice with no test/fault output
// -> infra flake, not kernel).  Audit: no divergent barriers; buffer hazards
// fenced (write->barrier->read per buffer; ostage overlays buf0, last read
// kg=6, fenced); all LDS/global addresses in bounds (B col 28-31 reads are
// in-buffer garbage zeroed in epilogue, same as verified R5); LDS 67.6 KB;
// v[32] constant-indexed.
//
// R11 theory (untested): effective BW ~2-3 TB/s regardless of pattern (R8:
// not latency; R10: perfect streamer hit 1.4 TB/s HBM) -> the lever is TOTAL
// BYTES + PASS COUNT.  Fusion: dot(a^,b^) = dot(a,b)*inv|a|*inv|b| -- MFMA on
// RAW fp16; each staging thread owns ONE pixel (512 thr = 448 b-halo + 64 a),
// reads its 32 c's per kg coalesced-across-lanes, accumulates f32 sumsq while
// packing fp16 into the EXACT R5 LDS layout; inv-norms in the epilogue
// (b: inv|b|; a: INV_T*inv|a|).  Eliminates norm pass, nt pass, 134 MB
// workspace round-trip, 2 launches.  ~178 MB HBM-unique vs ~450 MB.

typedef _Float16 half8 __attribute__((ext_vector_type(8)));
typedef float floatx4 __attribute__((ext_vector_type(4)));

#define B_ 4
#define C_ 256
#define H_ 128
#define W_ 128
#define K2_ 169
#define INV_T 14.285714285714286f
#define HW_ (H_ * W_)  // 16384

// LDS byte offsets (per 32 KB buffer), unchanged from R5:
//   b-px (row,col): halfs (row*28+col)*32 + c   [row 0..15, col 0..27]
//   a-px (r,m):     halfs 14336 + (r*16+m)*32 + c
// Frag reads: A[r] at 14336 + (r*16+ml)*32 + q*8 ; B at jj*896 + col*32 + q*8.
union SmemU { _Float16 stage[2][16384]; float ostage[K2_ * 2 * 17]; };  // 64 KB

__global__ __launch_bounds__(512, 4) void corr_fused(const float* __restrict__ fa,
                                                     const float* __restrict__ fb,
                                                     float* __restrict__ out) {
  __shared__ SmemU u;
  __shared__ float inv_b[448];
  __shared__ float inv_a[64];
  const int bid = blockIdx.x;
  const int xcd = bid & 7, l = bid >> 3;  // XCD-contiguous h-bands (halo L2 reuse)
  const int bb = l >> 5, hseg = (l >> 3) & 3, wt = l & 7;
  const int hg = xcd * 4 + hseg;
  const int h0 = hg * 4, w0 = wt * 16;
  const int t = threadIdx.x;
  const int lane = t & 63, wv = t >> 6;  // 8 waves
  const int ml = lane & 15, q = lane >> 4;
  const int ntile = wv & 1, jjg = wv >> 1;

  // ---- staging assignment: one thread per pixel, 32 c's per kg ----
  bool ok;
  const float* gp;
  int pxo;  // half offset of this px's row within a stage buffer
  if (t < 448) {  // b-halo: 16 rows x 28 cols
    const int row = t / 28, col = t - row * 28;
    const int rim = h0 - 6 + row, cim = w0 - 6 + col;
    ok = ((unsigned)rim < (unsigned)H_) && ((unsigned)cim < (unsigned)W_);
    gp = fb + (size_t)bb * C_ * HW_ + (ok ? (rim * W_ + cim) : 0);
    pxo = t * 32;
  } else {        // a-tile: 4 rows x 16 cols
    const int px = t - 448;
    const int r = px >> 4, m = px & 15;
    ok = true;
    gp = fa + (size_t)bb * C_ * HW_ + (h0 + r) * W_ + (w0 + m);
    pxo = 14336 + px * 32;
  }

  float ss = 0.f;   // f32 sumsq over all 256 c (full precision, raw values)
  float v[32];      // staged fp32 values for one kg (constant-indexed)

  // ---- prologue: stage kg=0 into buf0 ----
  #pragma unroll
  for (int cc = 0; cc < 32; ++cc) v[cc] = ok ? gp[(size_t)cc * HW_] : 0.f;
  gp += (size_t)32 * HW_;
  {
    _Float16* wb = u.stage[0] + pxo;
    #pragma unroll
    for (int qq = 0; qq < 4; ++qq) {
      half8 hh;
      #pragma unroll
      for (int j = 0; j < 8; ++j) { const float x = v[qq * 8 + j]; ss += x * x; hh[j] = (_Float16)x; }
      *(half8*)(wb + qq * 8) = hh;
    }
  }

  floatx4 acc[4][4] = {};  // [uu: jj=jjg+4uu][r]; 13 of 16 valid per wave

  for (int kg = 0; kg < 8; ++kg) {
    if (kg < 7) {  // issue next kg's loads early: latency hides under frag+MFMA
      #pragma unroll
      for (int cc = 0; cc < 32; ++cc) v[cc] = ok ? gp[(size_t)cc * HW_] : 0.f;
      gp += (size_t)32 * HW_;
    }
    __syncthreads();  // buf[kg&1] writes (prev iter / prologue) visible
    const _Float16* sb = u.stage[kg & 1];

    half8 A[4];
    #pragma unroll
    for (int r = 0; r < 4; ++r)
      A[r] = *(const half8*)(sb + 14336 + (r * 16 + ml) * 32 + q * 8);

    #pragma unroll
    for (int uu = 0; uu < 4; ++uu) {
      const int jj = jjg + 4 * uu;
      const half8 Bf = *(const half8*)(sb + jj * 896 + (ntile * 16 + ml) * 32 + q * 8);
      #pragma unroll
      for (int r = 0; r < 4; ++r) {
        if ((uu == 0 && r > jjg) || (uu == 3 && r < jjg)) continue;  // dy out of band
        acc[uu][r] = __builtin_amdgcn_mfma_f32_16x16x32_f16(A[r], Bf, acc[uu][r], 0, 0, 0);
      }
    }

    if (kg < 7) {  // consume staged regs -> other buffer (no barrier needed here)
      _Float16* wb = u.stage[(kg + 1) & 1] + pxo;
      #pragma unroll
      for (int qq = 0; qq < 4; ++qq) {
        half8 hh;
        #pragma unroll
        for (int j = 0; j < 8; ++j) { const float x = v[qq * 8 + j]; ss += x * x; hh[j] = (_Float16)x; }
        *(half8*)(wb + qq * 8) = hh;
      }
    }
  }

  // ---- inverse norms (f32, from raw f32 sumsq; OOB px: ss=0 -> dot=0 -> 0) ----
  if (t < 448) inv_b[t] = 1.0f / fmaxf(sqrtf(ss), 1e-12f);
  else         inv_a[t - 448] = INV_T / fmaxf(sqrtf(ss), 1e-12f);
  __syncthreads();  // also guarantees all waves are past the kg loop (ostage overlays buf0)

  // ---- epilogue: scale by inv-norms; 2 rounds of 2 rows; ostage overlays buf0 ----
  #pragma unroll
  for (int r2 = 0; r2 < 2; ++r2) {
    if (r2) __syncthreads();
    #pragma unroll
    for (int uu = 0; uu < 4; ++uu) {
      const int jj = jjg + 4 * uu;
      const int col = ntile * 16 + ml;
      const float sbv = (col < 28) ? inv_b[jj * 28 + col] : 0.f;  // col>=28 never stored
      #pragma unroll
      for (int rr = 2 * r2; rr < 2 * r2 + 2; ++rr) {
        if ((uu == 0 && rr > jjg) || (uu == 3 && rr < jjg)) continue;
        const int dy6 = jj - rr;  // in [0,12]
        #pragma unroll
        for (int p = 0; p < 4; ++p) {
          const int ip = q * 4 + p;
          const int dx6 = col - ip;
          if (dx6 >= 0 && dx6 <= 12)
            u.ostage[((dy6 * 13 + dx6) * 2 + (rr & 1)) * 17 + ip] =
                acc[uu][rr][p] * sbv * inv_a[rr * 16 + ip];
        }
      }
    }
    __syncthreads();
    for (int s = t; s < K2_ * 32; s += 512) {
      const int k = s >> 5, r1 = (s >> 4) & 1, ip = s & 15;
      out[(((size_t)bb * K2_ + k) * H_ + h0 + 2 * r2 + r1) * W_ + w0 + ip] =
          u.ostage[(k * 2 + r1) * 17 + ip];
    }
  }
}

extern "C" void kernel_launch(void* const* d_in, const int* in_sizes, int n_in,
                              void* d_out, int out_size, void* d_ws, size_t ws_size,
                              hipStream_t stream) {
  const float* fa = (const float*)d_in[0];
  const float* fb = (const float*)d_in[1];
  float* out = (float*)d_out;
  (void)d_ws; (void)ws_size;  // workspace no longer needed
  corr_fused<<<1024, 512, 0, stream>>>(fa, fb, out);
}